// Round 7
// baseline (4253.662 us; speedup 1.0000x reference)
//
#include <hip/hip_runtime.h>
#include <math.h>

#define Bn 128
#define Tn 256
#define Fn 36
#define Hn 128
#define G4 512
#define BTFn (Bn*Tn*Fn)

// workspace layout (floats)
#define INVD_OFF 0
#define LOSS_OFF 102656
#define IMP_OFF  103040

// ---- LDS word offsets ----
#define OFF_WHH    0       // [kk4<32][e<2][r<512] f16-pairs      : 32768
#define OFF_WHIST  32768   // [q<64][f<36]                        : 2304
#define OFF_WF     35072   // [q<18][g<36]                        : 648
#define OFF_WWC    35720   // [q<36][g<36]                        : 1296
#define OFF_IN     37016   // f32 [c<2][w<3][f<36] w:0=m,1=d,2=rt : 216
#define OFF_DP     37232   // [par<2][c<2] stride 20              : 80
#define OFF_MP     37312   // [par<2][c<2] stride 20              : 80
#define OFF_GXP    37392   // [c<2] stride 20                     : 40
#define OFF_XCP    37432   // [c<2] stride 20                     : 40
#define OFF_CCP    37472   // [c<2] stride 20                     : 40
#define OFF_ALPHA  37512   // f32 [c<2][36]                       : 72
#define OFF_HP     37584   // [c<2][64] f16-pairs                 : 128
#define OFF_GFA    37712   // f32 [c<2][512] (kk<10 partial, then final gates) : 1024
#define OFF_GFB    38736   // f32 [c<2][512] (kk>=10 partial)     : 1024
#define OFF_INVD   39760   // f32 [256]
#define OFF_BDH    40016   // f32 [128]
#define OFF_BH     40144
#define OFF_BF     40180
#define OFF_BWC    40216
#define OFF_WDXD   40252
#define OFF_BDX    40288   // +36 -> 40324 words
#define SMEM_WORDS 40324   // 161296 B <= 160 KiB

typedef _Float16 h2_t __attribute__((ext_vector_type(2)));

__device__ __forceinline__ unsigned int bcu(float x) { return __builtin_bit_cast(unsigned int, x); }
__device__ __forceinline__ unsigned int pkh(float a, float b) {
    return __builtin_bit_cast(unsigned int, __builtin_amdgcn_cvt_pkrtz(a, b));
}
__device__ __forceinline__ float dot2(unsigned int a, unsigned int b, float c) {
    return __builtin_amdgcn_fdot2(__builtin_bit_cast(h2_t, a), __builtin_bit_cast(h2_t, b), c, false);
}
__device__ __forceinline__ float sigmoid_f(float x) {
    return __builtin_amdgcn_rcpf(1.f + __expf(-x));
}
__device__ __forceinline__ float tanh_f(float x) {
    return fmaf(2.f, __builtin_amdgcn_rcpf(1.f + __expf(-2.f * x)), -1.f);
}

// ---------------- prep: inv-denom per t ----------------
__global__ void prep_kernel(const float* __restrict__ data,
                            float* __restrict__ ws) {
    int t = blockIdx.x;
    int tid = threadIdx.x;
    __shared__ float red[256];
    float s = 0.f;
    for (int idx = tid; idx < Bn * Fn; idx += 256) {
        int b = idx / Fn, f = idx - b * Fn;
        s += data[((size_t)(b * 24 + 1) * Tn + t) * Fn + f];
    }
    red[tid] = s;
    __syncthreads();
    for (int off = 128; off > 0; off >>= 1) {
        if (tid < off) red[tid] += red[tid + off];
        __syncthreads();
    }
    if (tid == 0) ws[INVD_OFF + t] = 1.f / (red[0] + 1e-5f);
}

#define LOAD18(dst, smem, base) do {                                      \
    float4 _a = *(const float4*)&(smem)[(base)];                          \
    float4 _b = *(const float4*)&(smem)[(base)+4];                        \
    float4 _c = *(const float4*)&(smem)[(base)+8];                        \
    float4 _d = *(const float4*)&(smem)[(base)+12];                       \
    float2 _e = *(const float2*)&(smem)[(base)+16];                       \
    dst[0]=bcu(_a.x);dst[1]=bcu(_a.y);dst[2]=bcu(_a.z);dst[3]=bcu(_a.w);  \
    dst[4]=bcu(_b.x);dst[5]=bcu(_b.y);dst[6]=bcu(_b.z);dst[7]=bcu(_b.w);  \
    dst[8]=bcu(_c.x);dst[9]=bcu(_c.y);dst[10]=bcu(_c.z);dst[11]=bcu(_c.w);\
    dst[12]=bcu(_d.x);dst[13]=bcu(_d.y);dst[14]=bcu(_d.z);dst[15]=bcu(_d.w);\
    dst[16]=bcu(_e.x);dst[17]=bcu(_e.y);                                  \
} while (0)

// ---------------- main: 512 threads, 2 chains, 3-phase schedule ----------------
__global__ __launch_bounds__(512) void rits_main(
    const float* __restrict__ data,
    const float* __restrict__ W_dh, const float* __restrict__ b_dh,
    const float* __restrict__ W_dx, const float* __restrict__ b_dx,
    const float* __restrict__ W_hist, const float* __restrict__ b_hist,
    const float* __restrict__ W_feat, const float* __restrict__ b_feat,
    const float* __restrict__ W_wc, const float* __restrict__ b_wc,
    const float* __restrict__ W_ih, const float* __restrict__ W_hh,
    const float* __restrict__ b_ih, const float* __restrict__ b_hh,
    const float* __restrict__ W_comb,
    float* __restrict__ ws) {

    extern __shared__ unsigned int smem[];
    float* smf = (float*)smem;

    const int tid = threadIdx.x;
    const int chainA = blockIdx.x * 2, chainB = chainA + 1;
    const int bA = chainA / 3, kA = chainA - 3 * bA;
    const int bB = chainB / 3, kB = chainB - 3 * bB;

    // ---- one-time staging ----
    for (int i = tid; i < 32768; i += 512) {
        int kk4 = i >> 10, rest = i & 1023, e = rest >> 9, r = rest & 511;
        float2 wv = *(const float2*)&W_hh[r * Hn + 4 * kk4 + 2 * e];
        smem[OFF_WHH + i] = pkh(wv.x, wv.y);
    }
    for (int i = tid; i < 64 * Fn; i += 512) {
        int q = i / Fn, f = i - q * Fn;
        float2 wv = *(const float2*)&W_hist[f * Hn + 2 * q];
        smem[OFF_WHIST + i] = pkh(wv.x, wv.y);
    }
    for (int i = tid; i < 18 * Fn; i += 512) {
        int q = i / Fn, g = i - q * Fn;
        float2 wv = *(const float2*)&W_feat[g * Fn + 2 * q];
        float w0 = (2 * q     == g) ? 0.f : wv.x;
        float w1 = (2 * q + 1 == g) ? 0.f : wv.y;
        smem[OFF_WF + i] = pkh(w0, w1);
    }
    for (int i = tid; i < 36 * Fn; i += 512) {
        int q = i / Fn, g = i - q * Fn;
        int col = (q < 18) ? 2 * q : Fn + 2 * (q - 18);
        float2 wv = *(const float2*)&W_wc[g * 2 * Fn + col];
        smem[OFF_WWC + i] = pkh(wv.x, wv.y);
    }
    if (tid < Hn) smf[OFF_BDH + tid] = b_dh[tid];
    if (tid < Fn) {
        smf[OFF_BH + tid] = b_hist[tid]; smf[OFF_BF + tid] = b_feat[tid];
        smf[OFF_BWC + tid] = b_wc[tid];  smf[OFF_WDXD + tid] = W_dx[tid * Fn + tid];
        smf[OFF_BDX + tid] = b_dx[tid];
    }
    for (int i = tid; i < Tn; i += 512) smf[OFF_INVD + i] = ws[INVD_OFF + i];

    // ---- per-row registers: W_ih pairs (36), W_dh pairs (18, tid<256 role) ----
    unsigned int wih[36];
    #pragma unroll
    for (int q = 0; q < 36; ++q) {
        float2 wv = *(const float2*)&W_ih[tid * 2 * Fn + 2 * q];
        wih[q] = pkh(wv.x, wv.y);
    }
    const float bias_j = b_ih[tid] + b_hh[tid];
    unsigned int wdh[18];
    {
        int hidx = tid & 127;
        #pragma unroll
        for (int q = 0; q < 18; ++q) {
            float2 wv = *(const float2*)&W_dh[hidx * Fn + 2 * q];
            wdh[q] = pkh(wv.x, wv.y);
        }
    }

    // ---- loader roles (tid>=256, idx<216): m,d,rt for both chains ----
    const float* ldsrc = nullptr; int lddst = 0, lc = 0, lf = 0; bool isd = false, ism = false;
    if (tid >= 256) {
        int idx = tid - 256;
        if (idx < 216) {
            int c = (idx >= 108); int r = idx - 108 * c;
            int w = r / Fn, f = r - w * Fn;
            int bb = c ? bB : bA, kk = c ? kB : kA;
            int row = (w == 0) ? 1 : (w == 1) ? 2 : (3 + 3 * kk);
            ldsrc = data + (size_t)(bb * 24 + row) * Tn * Fn + f;
            lddst = OFF_IN + c * 108 + w * Fn + f;
            isd = (w == 1); ism = (w == 0); lc = c; lf = f;
            float v = ldsrc[0];
            smf[lddst] = v;
            float vn = __shfl_xor(v, 1);
            if (isd && !(f & 1)) smem[OFF_DP + lc * 20 + (f >> 1)] = pkh(v, vn);
            if (ism && !(f & 1)) smem[OFF_MP + lc * 20 + (f >> 1)] = pkh(v, vn);
        }
    }

    // ---- waves 0-1 PhaseB role: tr/se direct global loads ----
    const int cb = tid >> 6;                 // valid for tid<128
    const int myb = cb ? bB : bA, myk = cb ? kB : kA;
    const float* trsrc = data + (size_t)(myb * 24 + 4 + 3 * myk) * Tn * Fn + (tid & 63);
    const float* sesrc = data + (size_t)(myb * 24 + 5 + 3 * myk) * Tn * Fn + (tid & 63);
    float* impPtr = ws + IMP_OFF + (size_t)((cb ? kB : kA) * Bn + (cb ? bB : bA)) * Tn * Fn;

    float h_reg = 0.f, c_reg = 0.f, loss_acc = 0.f;
    __syncthreads();

    for (int t = 0; t < Tn; ++t) {
        const int cur = t & 1, nxt = cur ^ 1;

        // =========== PhaseA: LSTM(t-1) + decay + gm + alpha/gx + load issue ===========
        float pf = 0.f, tr_v = 0.f, se_v = 0.f;
        if (tid < 128 && (tid & 63) < Fn) {
            tr_v = trsrc[(size_t)t * Fn];
            se_v = sesrc[(size_t)t * Fn];
        }
        if (ldsrc) pf = ldsrc[(size_t)(t + 1) * Fn];   // t=255 reads next channel: safe, unused

        if (tid < 256) {
            const int c = tid >> 7, hidx = tid & 127;
            if (t) {   // LSTM finishing step t-1
                float ig = smf[OFF_GFA + c * G4 + hidx];
                float fg = smf[OFF_GFA + c * G4 + 128 + hidx];
                float gg = smf[OFF_GFA + c * G4 + 256 + hidx];
                float og = smf[OFF_GFA + c * G4 + 384 + hidx];
                c_reg = sigmoid_f(fg) * c_reg + sigmoid_f(ig) * tanh_f(gg);
                h_reg = sigmoid_f(og) * tanh_f(c_reg);
            }
            // decay with d(t)
            const int db = OFF_DP + (cur * 2 + c) * 20;
            float g0 = smf[OFF_BDH + hidx], g1 = 0.f;
            #pragma unroll
            for (int q = 0; q < 18; q += 2) {
                g0 = dot2(smem[db + q], wdh[q], g0);
                g1 = dot2(smem[db + q + 1], wdh[q + 1], g1);
            }
            h_reg *= __expf(-fmaxf(g0 + g1, 0.f));
            float hn = __shfl_xor(h_reg, 1);
            if (!(hidx & 1)) smem[OFF_HP + c * 64 + (hidx >> 1)] = pkh(h_reg, hn);
        } else if (tid < 384) {
            const int c = (tid >> 6) & 1, lane = tid & 63;
            if (lane < Fn) {
                float d = smf[OFF_IN + c * 108 + Fn + lane];
                float gx = __expf(-fmaxf(fmaf(d, smf[OFF_WDXD + lane], smf[OFF_BDX + lane]), 0.f));
                float gxn = __shfl_xor(gx, 1);
                if (!(lane & 1)) smem[OFF_GXP + c * 20 + (lane >> 1)] = pkh(gx, gxn);
                float a0 = smf[OFF_BWC + lane], a1 = 0.f;
                #pragma unroll
                for (int q = 0; q < 18; ++q)
                    a0 = dot2(smem[OFF_GXP + c * 20 + q], smem[OFF_WWC + q * Fn + lane], a0);
                #pragma unroll
                for (int q = 0; q < 18; ++q)
                    a1 = dot2(smem[OFF_MP + (cur * 2 + c) * 20 + q], smem[OFF_WWC + (18 + q) * Fn + lane], a1);
                smf[OFF_ALPHA + c * Fn + lane] = a0 + a1;
            }
        }
        // gm: m-part of ih-gates for row j=tid, both chains (m(t) known since last step)
        float gmA, gmB;
        {
            unsigned int buf[18];
            LOAD18(buf, smem, OFF_MP + cur * 40);
            float a0 = 0.f, a1 = 0.f;
            #pragma unroll
            for (int q = 0; q < 18; q += 2) {
                a0 = dot2(buf[q], wih[18 + q], a0);
                a1 = dot2(buf[q + 1], wih[18 + q + 1], a1);
            }
            gmA = a0 + a1;
            LOAD18(buf, smem, OFF_MP + cur * 40 + 20);
            float b0 = 0.f, b1 = 0.f;
            #pragma unroll
            for (int q = 0; q < 18; q += 2) {
                b0 = dot2(buf[q], wih[18 + q], b0);
                b1 = dot2(buf[q + 1], wih[18 + q + 1], b1);
            }
            gmB = b0 + b1;
        }
        __syncthreads();   // B1

        // =========== PhaseB: features+cc+loss+imp (w0-1) | hh kk<10 (w2-3) | hh kk>=10 (w4-7) ===========
        if (tid < 128) {
            const int c = cb, f = tid & 63;
            if (f < Fn) {
                float a0 = smf[OFF_BH + f], a1 = 0.f, a2 = 0.f, a3 = 0.f;
                #pragma unroll
                for (int ch = 0; ch < 8; ++ch) {
                    float4 hL = *(const float4*)&smem[OFF_HP + c * 64 + ch * 8];
                    float4 hH = *(const float4*)&smem[OFF_HP + c * 64 + ch * 8 + 4];
                    a0 = dot2(bcu(hL.x), smem[OFF_WHIST + (ch * 8 + 0) * Fn + f], a0);
                    a1 = dot2(bcu(hL.y), smem[OFF_WHIST + (ch * 8 + 1) * Fn + f], a1);
                    a2 = dot2(bcu(hL.z), smem[OFF_WHIST + (ch * 8 + 2) * Fn + f], a2);
                    a3 = dot2(bcu(hL.w), smem[OFF_WHIST + (ch * 8 + 3) * Fn + f], a3);
                    a0 = dot2(bcu(hH.x), smem[OFF_WHIST + (ch * 8 + 4) * Fn + f], a0);
                    a1 = dot2(bcu(hH.y), smem[OFF_WHIST + (ch * 8 + 5) * Fn + f], a1);
                    a2 = dot2(bcu(hH.z), smem[OFF_WHIST + (ch * 8 + 6) * Fn + f], a2);
                    a3 = dot2(bcu(hH.w), smem[OFF_WHIST + (ch * 8 + 7) * Fn + f], a3);
                }
                float xh = (a0 + a1) + (a2 + a3);
                float m  = smf[OFF_IN + c * 108 + f];
                float rt = smf[OFF_IN + c * 108 + 72 + f];
                float xc = m * rt + (1.f - m) * xh;
                float xcn = __shfl_xor(xc, 1);
                if (!(f & 1)) smem[OFF_XCP + c * 20 + (f >> 1)] = pkh(xc, xcn);
                float z0 = smf[OFF_BF + f], z1 = 0.f;
                #pragma unroll
                for (int q = 0; q < 18; q += 2) {
                    z0 = dot2(smem[OFF_XCP + c * 20 + q], smem[OFF_WF + q * Fn + f], z0);
                    z1 = dot2(smem[OFF_XCP + c * 20 + q + 1], smem[OFF_WF + (q + 1) * Fn + f], z1);
                }
                float zh = z0 + z1;
                float al = smf[OFF_ALPHA + c * Fn + f];
                float chv = al * zh + (1.f - al) * xh;
                float cc = m * rt + (1.f - m) * chv;
                loss_acc = fmaf((fabsf(rt - xh) + fabsf(rt - zh) + fabsf(rt - chv)) * m,
                                smf[OFF_INVD + t], loss_acc);
                impPtr[t * Fn + f] = cc + se_v + tr_v;
                float ccn = __shfl_xor(cc, 1);
                if (!(f & 1)) smem[OFF_CCP + c * 20 + (f >> 1)] = pkh(cc, ccn);
            }
        } else if (tid < 256) {
            const int u = tid - 128;       // rows 4u..4u+3, kk4 in [0,10)
            #pragma unroll
            for (int c = 0; c < 2; ++c) {
                float a0 = 0.f, a1 = 0.f, a2 = 0.f, a3 = 0.f;
                #pragma unroll
                for (int kk = 0; kk < 10; ++kk) {
                    float2 hp2 = *(const float2*)&smem[OFF_HP + c * 64 + 2 * kk];
                    unsigned int hp0 = bcu(hp2.x), hp1 = bcu(hp2.y);
                    float4 w0 = *(const float4*)&smem[OFF_WHH + kk * 1024 + 4 * u];
                    float4 w1 = *(const float4*)&smem[OFF_WHH + kk * 1024 + 512 + 4 * u];
                    a0 = dot2(hp0, bcu(w0.x), a0); a1 = dot2(hp0, bcu(w0.y), a1);
                    a2 = dot2(hp0, bcu(w0.z), a2); a3 = dot2(hp0, bcu(w0.w), a3);
                    a0 = dot2(hp1, bcu(w1.x), a0); a1 = dot2(hp1, bcu(w1.y), a1);
                    a2 = dot2(hp1, bcu(w1.z), a2); a3 = dot2(hp1, bcu(w1.w), a3);
                }
                float4 v; v.x = a0; v.y = a1; v.z = a2; v.w = a3;
                *(float4*)&smf[OFF_GFA + c * G4 + 4 * u] = v;
            }
        } else {
            const int r0 = tid - 256, r1 = tid;   // kk4 in [10,32)
            float A0 = 0.f, A1 = 0.f, B0 = 0.f, B1v = 0.f;
            float C0 = 0.f, C1 = 0.f, D0 = 0.f, D1 = 0.f;
            #pragma unroll
            for (int kk = 10; kk < 32; ++kk) {
                float2 ha = *(const float2*)&smem[OFF_HP + 2 * kk];
                float2 hb = *(const float2*)&smem[OFF_HP + 64 + 2 * kk];
                unsigned int hp00 = bcu(ha.x), hp01 = bcu(ha.y);
                unsigned int hp10 = bcu(hb.x), hp11 = bcu(hb.y);
                unsigned int w00 = smem[OFF_WHH + kk * 1024 + r0];
                unsigned int w01 = smem[OFF_WHH + kk * 1024 + 512 + r0];
                unsigned int w10 = smem[OFF_WHH + kk * 1024 + r1];
                unsigned int w11 = smem[OFF_WHH + kk * 1024 + 512 + r1];
                A0 = dot2(hp00, w00, A0); A1 = dot2(hp01, w01, A1);
                B0 = dot2(hp10, w00, B0); B1v = dot2(hp11, w01, B1v);
                C0 = dot2(hp00, w10, C0); C1 = dot2(hp01, w11, C1);
                D0 = dot2(hp10, w10, D0); D1 = dot2(hp11, w11, D1);
            }
            smf[OFF_GFB + r0] = A0 + A1;       smf[OFF_GFB + G4 + r0] = B0 + B1v;
            smf[OFF_GFB + r1] = C0 + C1;       smf[OFF_GFB + G4 + r1] = D0 + D1;
        }
        __syncthreads();   // B2

        // =========== PhaseC: gate finalize (all rows) + input writes ===========
        {
            const int j = tid;
            unsigned int buf[18];
            float gA0 = bias_j + gmA + smf[OFF_GFA + j] + smf[OFF_GFB + j];
            float gA1 = 0.f;
            LOAD18(buf, smem, OFF_CCP);
            #pragma unroll
            for (int q = 0; q < 18; q += 2) {
                gA0 = dot2(buf[q], wih[q], gA0);
                gA1 = dot2(buf[q + 1], wih[q + 1], gA1);
            }
            float gB0 = bias_j + gmB + smf[OFF_GFA + G4 + j] + smf[OFF_GFB + G4 + j];
            float gB1 = 0.f;
            LOAD18(buf, smem, OFF_CCP + 20);
            #pragma unroll
            for (int q = 0; q < 18; q += 2) {
                gB0 = dot2(buf[q], wih[q], gB0);
                gB1 = dot2(buf[q + 1], wih[q + 1], gB1);
            }
            smf[OFF_GFA + j] = gA0 + gA1;
            smf[OFF_GFA + G4 + j] = gB0 + gB1;
        }
        if (ldsrc) {
            smf[lddst] = pf;
            float vn = __shfl_xor(pf, 1);
            if (isd && !(lf & 1)) smem[OFF_DP + (nxt * 2 + lc) * 20 + (lf >> 1)] = pkh(pf, vn);
            if (ism && !(lf & 1)) smem[OFF_MP + (nxt * 2 + lc) * 20 + (lf >> 1)] = pkh(pf, vn);
        }
        __syncthreads();   // B3
    }

    // ---- per-block loss partial (fixed order -> deterministic) ----
    if (tid < 128) {
        const int c = cb, f = tid & 63;
        if (f < Fn) smf[OFF_GFA + c * Fn + f] = loss_acc;
    }
    __syncthreads();
    if (tid == 0) {
        float sA = 0.f, sB = 0.f;
        for (int i = 0; i < Fn; ++i) { sA += smf[OFF_GFA + i]; sB += smf[OFF_GFA + Fn + i]; }
        float w0 = W_comb[0], w1 = W_comb[1], w2 = W_comb[2];
        float mx = fmaxf(w0, fmaxf(w1, w2));
        float e0 = expf(w0 - mx), e1 = expf(w1 - mx), e2 = expf(w2 - mx);
        float inv = 1.f / (e0 + e1 + e2);
        float wkA = ((kA == 0) ? e0 : (kA == 1) ? e1 : e2) * inv;
        float wkB = ((kB == 0) ? e0 : (kB == 1) ? e1 : e2) * inv;
        ws[LOSS_OFF + blockIdx.x] = sA * wkA + sB * wkB;
    }
}

// ---------------- k-reduction of imputations ----------------
__global__ void impute_reduce(const float* __restrict__ ws,
                              const float* __restrict__ W_comb,
                              float* __restrict__ out) {
    int idx = blockIdx.x * 256 + threadIdx.x;
    float w0 = W_comb[0], w1 = W_comb[1], w2 = W_comb[2];
    float mx = fmaxf(w0, fmaxf(w1, w2));
    float e0 = expf(w0 - mx), e1 = expf(w1 - mx), e2 = expf(w2 - mx);
    float inv = 1.f / (e0 + e1 + e2);
    const float* imp = ws + IMP_OFF;
    out[1 + idx] = (e0 * imp[idx] + e1 * imp[BTFn + idx] + e2 * imp[2 * BTFn + idx]) * inv;
}

// ---------------- final loss (192 per-block partials) ----------------
__global__ void loss_final(const float* __restrict__ ws,
                           const float* __restrict__ W_comb,
                           float* __restrict__ out) {
    int tid = threadIdx.x;
    __shared__ float red[256];
    const float* lp = ws + LOSS_OFF;
    red[tid] = (tid < 192) ? lp[tid] : 0.f;
    __syncthreads();
    for (int off = 128; off > 0; off >>= 1) {
        if (tid < off) red[tid] += red[tid + off];
        __syncthreads();
    }
    if (tid == 0) {
        float w0 = W_comb[0], w1 = W_comb[1], w2 = W_comb[2];
        float mx = fmaxf(w0, fmaxf(w1, w2));
        float e0 = expf(w0 - mx), e1 = expf(w1 - mx), e2 = expf(w2 - mx);
        float inv = 1.f / (e0 + e1 + e2);
        float wk0 = e0 * inv, wk1 = e1 * inv, wk2 = e2 * inv;
        float reg = 0.1f * (wk0 * (1.f / 24.f) + wk1 * (1.f / 168.f) + wk2 * (1.f / 720.f));
        out[0] = red[0] + (float)Tn * reg;
    }
}

extern "C" void kernel_launch(void* const* d_in, const int* in_sizes, int n_in,
                              void* d_out, int out_size, void* d_ws, size_t ws_size,
                              hipStream_t stream) {
    const float* data   = (const float*)d_in[0];
    const float* W_dh   = (const float*)d_in[1];
    const float* b_dh   = (const float*)d_in[2];
    const float* W_dx   = (const float*)d_in[3];
    const float* b_dx   = (const float*)d_in[4];
    const float* W_hist = (const float*)d_in[5];
    const float* b_hist = (const float*)d_in[6];
    const float* W_feat = (const float*)d_in[7];
    const float* b_feat = (const float*)d_in[8];
    const float* W_wc   = (const float*)d_in[9];
    const float* b_wc   = (const float*)d_in[10];
    const float* W_ih   = (const float*)d_in[11];
    const float* W_hh   = (const float*)d_in[12];
    const float* b_ih   = (const float*)d_in[13];
    const float* b_hh   = (const float*)d_in[14];
    const float* W_comb = (const float*)d_in[15];
    float* ws = (float*)d_ws;
    float* out = (float*)d_out;

    hipLaunchKernelGGL(prep_kernel, dim3(Tn), dim3(256), 0, stream, data, ws);
    hipLaunchKernelGGL(rits_main, dim3(Bn * 3 / 2), dim3(512), SMEM_WORDS * 4, stream,
                       data, W_dh, b_dh, W_dx, b_dx, W_hist, b_hist,
                       W_feat, b_feat, W_wc, b_wc, W_ih, W_hh, b_ih, b_hh, W_comb, ws);
    hipLaunchKernelGGL(impute_reduce, dim3(BTFn / 256), dim3(256), 0, stream, ws, W_comb, out);
    hipLaunchKernelGGL(loss_final, dim3(1), dim3(256), 0, stream, ws, W_comb, out);
}

// Round 8
// 2332.993 us; speedup vs baseline: 1.8233x; 1.8233x over previous
//
#include <hip/hip_runtime.h>
#include <math.h>

#define Bn 128
#define Tn 256
#define Fn 36
#define Hn 128
#define G4 512
#define BTFn (Bn*Tn*Fn)

// workspace layout (floats)
#define INVD_OFF 0
#define LOSS_OFF 102656
#define IMP_OFF  103040

// ---- LDS word offsets ----
#define OFF_WHH    0       // [kk4<32][r<512][e<2] f16-pairs (round-6 layout) : 32768
#define OFF_WHIST  32768   // [q<64][f<36]                                   : 2304
#define OFF_WF     35072   // [q<18][g<36] diag-zeroed                       : 648
#define OFF_WWC    35720   // [q<36][g<36]                                   : 1296
#define OFF_IN     37016   // f32 [c<2][w<5][f<36] m,d,rt,tr,se              : 360
#define OFF_DP     37376   // [par<2][c<2] stride 20                         : 80
#define OFF_MP     37456   // [par<2][c<2] stride 20                         : 80
#define OFF_GXP    37536   // [c<2] stride 20                                : 40
#define OFF_CCP    37576   // [c<2] stride 20                                : 40
#define OFF_HP     37616   // [c<2][64] f16-pairs                            : 128
#define OFF_GFA    37744   // f32 [c<2][512] hh kk<10 partial -> final gates : 1024
#define OFF_GFB    38768   // f32 [c<2][512] hh kk>=10 partial               : 1024
#define OFF_INVD   39792   // f32 [256]
#define OFF_BDH    40048   // f32 [128]
#define OFF_BH     40176
#define OFF_BF     40212
#define OFF_BWC    40248
#define OFF_WDXD   40284
#define OFF_BDX    40320   // +36 -> 40356 words
#define SMEM_WORDS 40356   // 161424 B <= 160 KiB

typedef _Float16 h2_t __attribute__((ext_vector_type(2)));

__device__ __forceinline__ unsigned int bcu(float x) { return __builtin_bit_cast(unsigned int, x); }
__device__ __forceinline__ unsigned int pkh(float a, float b) {
    return __builtin_bit_cast(unsigned int, __builtin_amdgcn_cvt_pkrtz(a, b));
}
__device__ __forceinline__ float dot2(unsigned int a, unsigned int b, float c) {
    return __builtin_amdgcn_fdot2(__builtin_bit_cast(h2_t, a), __builtin_bit_cast(h2_t, b), c, false);
}
__device__ __forceinline__ float sigmoid_f(float x) {
    return __builtin_amdgcn_rcpf(1.f + __expf(-x));
}
__device__ __forceinline__ float tanh_f(float x) {
    return fmaf(2.f, __builtin_amdgcn_rcpf(1.f + __expf(-2.f * x)), -1.f);
}

// ---------------- prep: inv-denom per t ----------------
__global__ void prep_kernel(const float* __restrict__ data,
                            float* __restrict__ ws) {
    int t = blockIdx.x;
    int tid = threadIdx.x;
    __shared__ float red[256];
    float s = 0.f;
    for (int idx = tid; idx < Bn * Fn; idx += 256) {
        int b = idx / Fn, f = idx - b * Fn;
        s += data[((size_t)(b * 24 + 1) * Tn + t) * Fn + f];
    }
    red[tid] = s;
    __syncthreads();
    for (int off = 128; off > 0; off >>= 1) {
        if (tid < off) red[tid] += red[tid + off];
        __syncthreads();
    }
    if (tid == 0) ws[INVD_OFF + t] = 1.f / (red[0] + 1e-5f);
}

// 18 packed dots from an LDS base into acc (float4-chunk loads, consumed immediately)
#define DOT18C(acc, base, woff) do {                                   \
    const unsigned int* _p = &smem[(base)];                            \
    float4 _v0 = *(const float4*)_p;                                   \
    float4 _v1 = *(const float4*)(_p + 4);                             \
    acc = dot2(bcu(_v0.x), wih[(woff) + 0], acc);                      \
    acc = dot2(bcu(_v0.y), wih[(woff) + 1], acc);                      \
    acc = dot2(bcu(_v0.z), wih[(woff) + 2], acc);                      \
    acc = dot2(bcu(_v0.w), wih[(woff) + 3], acc);                      \
    float4 _v2 = *(const float4*)(_p + 8);                             \
    acc = dot2(bcu(_v1.x), wih[(woff) + 4], acc);                      \
    acc = dot2(bcu(_v1.y), wih[(woff) + 5], acc);                      \
    acc = dot2(bcu(_v1.z), wih[(woff) + 6], acc);                      \
    acc = dot2(bcu(_v1.w), wih[(woff) + 7], acc);                      \
    float4 _v3 = *(const float4*)(_p + 12);                            \
    acc = dot2(bcu(_v2.x), wih[(woff) + 8], acc);                      \
    acc = dot2(bcu(_v2.y), wih[(woff) + 9], acc);                      \
    acc = dot2(bcu(_v2.z), wih[(woff) + 10], acc);                     \
    acc = dot2(bcu(_v2.w), wih[(woff) + 11], acc);                     \
    float2 _v4 = *(const float2*)(_p + 16);                            \
    acc = dot2(bcu(_v3.x), wih[(woff) + 12], acc);                     \
    acc = dot2(bcu(_v3.y), wih[(woff) + 13], acc);                     \
    acc = dot2(bcu(_v3.z), wih[(woff) + 14], acc);                     \
    acc = dot2(bcu(_v3.w), wih[(woff) + 15], acc);                     \
    acc = dot2(bcu(_v4.x), wih[(woff) + 16], acc);                     \
    acc = dot2(bcu(_v4.y), wih[(woff) + 17], acc);                     \
} while (0)

// ---------------- main: 512 threads, 2 chains, 3-barrier schedule ----------------
__global__ __launch_bounds__(512) void rits_main(
    const float* __restrict__ data,
    const float* __restrict__ W_dh, const float* __restrict__ b_dh,
    const float* __restrict__ W_dx, const float* __restrict__ b_dx,
    const float* __restrict__ W_hist, const float* __restrict__ b_hist,
    const float* __restrict__ W_feat, const float* __restrict__ b_feat,
    const float* __restrict__ W_wc, const float* __restrict__ b_wc,
    const float* __restrict__ W_ih, const float* __restrict__ W_hh,
    const float* __restrict__ b_ih, const float* __restrict__ b_hh,
    const float* __restrict__ W_comb,
    float* __restrict__ ws) {

    extern __shared__ unsigned int smem[];
    float* smf = (float*)smem;

    const int tid = threadIdx.x;
    const int chainA = blockIdx.x * 2, chainB = chainA + 1;
    const int bA = chainA / 3, kA = chainA - 3 * bA;
    const int bB = chainB / 3, kB = chainB - 3 * bB;

    // ---- one-time staging (round-6 layouts) ----
    for (int i = tid; i < 32768; i += 512) {
        int kk4 = i >> 10, rest = i & 1023, r = rest >> 1, e = rest & 1;
        float2 wv = *(const float2*)&W_hh[r * Hn + 4 * kk4 + 2 * e];
        smem[OFF_WHH + i] = pkh(wv.x, wv.y);
    }
    for (int i = tid; i < 64 * Fn; i += 512) {
        int q = i / Fn, f = i - q * Fn;
        float2 wv = *(const float2*)&W_hist[f * Hn + 2 * q];
        smem[OFF_WHIST + i] = pkh(wv.x, wv.y);
    }
    for (int i = tid; i < 18 * Fn; i += 512) {
        int q = i / Fn, g = i - q * Fn;
        float2 wv = *(const float2*)&W_feat[g * Fn + 2 * q];
        float w0 = (2 * q     == g) ? 0.f : wv.x;
        float w1 = (2 * q + 1 == g) ? 0.f : wv.y;
        smem[OFF_WF + i] = pkh(w0, w1);
    }
    for (int i = tid; i < 36 * Fn; i += 512) {
        int q = i / Fn, g = i - q * Fn;
        int col = (q < 18) ? 2 * q : Fn + 2 * (q - 18);
        float2 wv = *(const float2*)&W_wc[g * 2 * Fn + col];
        smem[OFF_WWC + i] = pkh(wv.x, wv.y);
    }
    if (tid < Hn) smf[OFF_BDH + tid] = b_dh[tid];
    if (tid < Fn) {
        smf[OFF_BH + tid] = b_hist[tid]; smf[OFF_BF + tid] = b_feat[tid];
        smf[OFF_BWC + tid] = b_wc[tid];  smf[OFF_WDXD + tid] = W_dx[tid * Fn + tid];
        smf[OFF_BDX + tid] = b_dx[tid];
    }
    for (int i = tid; i < Tn; i += 512) smf[OFF_INVD + i] = ws[INVD_OFF + i];

    // ---- per-row registers ----
    unsigned int wih[36];
    #pragma unroll
    for (int q = 0; q < 36; ++q) {
        float2 wv = *(const float2*)&W_ih[tid * 2 * Fn + 2 * q];
        wih[q] = pkh(wv.x, wv.y);
    }
    const float bias_j = b_ih[tid] + b_hh[tid];
    unsigned int wdh[18];
    {
        int hidx = tid & 127;
        #pragma unroll
        for (int q = 0; q < 18; ++q) {
            float2 wv = *(const float2*)&W_dh[hidx * Fn + 2 * q];
            wdh[q] = pkh(wv.x, wv.y);
        }
    }

    // ---- loader roles (round-6 mapping): slot1 e=idx, slot2 e=idx+256 ----
    const float* ldsrc1 = nullptr; int lddst1 = 0, c1 = 0, f1 = 0; bool isd1 = false, ism1 = false;
    const float* ldsrc2 = nullptr; int lddst2 = -1;
    if (tid >= 256) {
        int idx = tid - 256;
        {
            int e = idx; int c = (e >= 180); int r = e - c * 180;
            int w = r / Fn, f = r - w * Fn;
            int bb = c ? bB : bA, kk = c ? kB : kA;
            int row = (w == 0) ? 1 : (w == 1) ? 2 : (3 + 3 * kk + (w - 2));
            ldsrc1 = data + (size_t)(bb * 24 + row) * Tn * Fn + f;
            lddst1 = OFF_IN + (c * 5 + w) * Fn + f;
            isd1 = (w == 1); ism1 = (w == 0); c1 = c; f1 = f;
        }
        if (idx < 104) {
            int e = idx + 256; int r = e - 180;           // always chain 1
            int w = r / Fn, f = r - w * Fn;
            int row = 3 + 3 * kB + (w - 2);
            ldsrc2 = data + (size_t)(bB * 24 + row) * Tn * Fn + f;
            lddst2 = OFF_IN + (5 + w) * Fn + f;
        }
        // prologue t=0 -> IN + d/m packs (parity 0)
        float v1 = ldsrc1[0];
        smf[lddst1] = v1;
        float v1n = __shfl_xor(v1, 1);
        if (isd1 && !(f1 & 1)) smem[OFF_DP + c1 * 20 + (f1 >> 1)] = pkh(v1, v1n);
        if (ism1 && !(f1 & 1)) smem[OFF_MP + c1 * 20 + (f1 >> 1)] = pkh(v1, v1n);
        if (ldsrc2) smf[lddst2] = ldsrc2[0];
    }

    float* impPtr = nullptr;
    if (tid < 128) {
        int c = tid >> 6;
        int mb_ = c ? bB : bA, mk_ = c ? kB : kA;
        impPtr = ws + IMP_OFF + (size_t)(mk_ * Bn + mb_) * Tn * Fn;
    }

    float h_reg = 0.f, c_reg = 0.f, loss_acc = 0.f;
    float gmA = 0.f, gmB = 0.f;
    __syncthreads();

    // prologue gm for t=0 (m-part of ih gates, parity 0)
    DOT18C(gmA, OFF_MP + 0, 18);
    DOT18C(gmB, OFF_MP + 20, 18);

    for (int t = 0; t < Tn; ++t) {
        const int cur = t & 1, nxt = cur ^ 1;

        // ---- issue t+1 input loads (hide under P2..P5) ----
        float pf1v = 0.f, pf2v = 0.f;
        if (tid >= 256) {
            pf1v = ldsrc1[(size_t)(t + 1) * Fn];     // t=255 reads next channel: safe, unused
            if (ldsrc2) pf2v = ldsrc2[(size_t)(t + 1) * Fn];
        }

        // ======== P2: decay h + pack hp (w0-3); gamma_x + pack (w4-5) ========
        if (tid < 256) {
            const int c = tid >> 7, hidx = tid & 127;
            const int db = OFF_DP + (cur * 2 + c) * 20;
            float g0 = smf[OFF_BDH + hidx], g1 = 0.f;
            #pragma unroll
            for (int q = 0; q < 18; q += 2) {
                g0 = dot2(smem[db + q], wdh[q], g0);
                g1 = dot2(smem[db + q + 1], wdh[q + 1], g1);
            }
            h_reg *= __expf(-fmaxf(g0 + g1, 0.f));
            float hn = __shfl_xor(h_reg, 1);
            if (!(hidx & 1)) smem[OFF_HP + c * 64 + (hidx >> 1)] = pkh(h_reg, hn);
        } else if (tid < 384) {
            const int c = (tid >> 6) & 1, lane = tid & 63;
            if (lane < Fn) {
                float d = smf[OFF_IN + (c * 5 + 1) * Fn + lane];
                float gx = __expf(-fmaxf(fmaf(d, smf[OFF_WDXD + lane], smf[OFF_BDX + lane]), 0.f));
                float gxn = __shfl_xor(gx, 1);
                if (!(lane & 1)) smem[OFF_GXP + c * 20 + (lane >> 1)] = pkh(gx, gxn);
            }
        }
        __syncthreads();   // B1

        // ======== P3: full feature pipeline (w0-1) | hh kk<10 (w2-3) | hh kk>=10 (w4-7) ========
        if (tid < 128) {
            const int c = tid >> 6, f = tid & 63;
            const int inb = OFF_IN + c * 180;
            float m  = smf[inb + f];
            float rt = smf[inb + 72 + f];
            // x_h
            float a0 = smf[OFF_BH + f], a1 = 0.f, a2 = 0.f, a3 = 0.f;
            #pragma unroll
            for (int ch = 0; ch < 8; ++ch) {
                float4 hL = *(const float4*)&smem[OFF_HP + c * 64 + ch * 8];
                float4 hH = *(const float4*)&smem[OFF_HP + c * 64 + ch * 8 + 4];
                a0 = dot2(bcu(hL.x), smem[OFF_WHIST + (ch * 8 + 0) * Fn + f], a0);
                a1 = dot2(bcu(hL.y), smem[OFF_WHIST + (ch * 8 + 1) * Fn + f], a1);
                a2 = dot2(bcu(hL.z), smem[OFF_WHIST + (ch * 8 + 2) * Fn + f], a2);
                a3 = dot2(bcu(hL.w), smem[OFF_WHIST + (ch * 8 + 3) * Fn + f], a3);
                a0 = dot2(bcu(hH.x), smem[OFF_WHIST + (ch * 8 + 4) * Fn + f], a0);
                a1 = dot2(bcu(hH.y), smem[OFF_WHIST + (ch * 8 + 5) * Fn + f], a1);
                a2 = dot2(bcu(hH.z), smem[OFF_WHIST + (ch * 8 + 6) * Fn + f], a2);
                a3 = dot2(bcu(hH.w), smem[OFF_WHIST + (ch * 8 + 7) * Fn + f], a3);
            }
            float xh = (a0 + a1) + (a2 + a3);
            float xc = m * rt + (1.f - m) * xh;
            // z_h via in-register shfl packing (no LDS round-trip, no barrier)
            float z0 = smf[OFF_BF + f], z1 = 0.f;
            #pragma unroll
            for (int q = 0; q < 18; q += 2) {
                float e0 = __shfl(xc, 2 * q, 64),     e1 = __shfl(xc, 2 * q + 1, 64);
                z0 = dot2(pkh(e0, e1), smem[OFF_WF + q * Fn + f], z0);
                float e2 = __shfl(xc, 2 * q + 2, 64), e3 = __shfl(xc, 2 * q + 3, 64);
                z1 = dot2(pkh(e2, e3), smem[OFF_WF + (q + 1) * Fn + f], z1);
            }
            float zh = z0 + z1;
            // alpha (broadcast gxp/mp reads)
            float al0 = smf[OFF_BWC + f], al1 = 0.f;
            const int gxb = OFF_GXP + c * 20;
            const int mpb = OFF_MP + cur * 40 + c * 20;
            #pragma unroll
            for (int q = 0; q < 18; ++q) {
                al0 = dot2(smem[gxb + q], smem[OFF_WWC + q * Fn + f], al0);
                al1 = dot2(smem[mpb + q], smem[OFF_WWC + (18 + q) * Fn + f], al1);
            }
            float al = al0 + al1;
            float chv = al * zh + (1.f - al) * xh;
            float cc = m * rt + (1.f - m) * chv;
            if (f < Fn) {
                loss_acc = fmaf((fabsf(rt - xh) + fabsf(rt - zh) + fabsf(rt - chv)) * m,
                                smf[OFF_INVD + t], loss_acc);
                float tr = smf[inb + 108 + f], se = smf[inb + 144 + f];
                impPtr[t * Fn + f] = cc + se + tr;
            }
            float ccn = __shfl_xor(cc, 1);
            if (!(f & 1) && f < Fn) smem[OFF_CCP + c * 20 + (f >> 1)] = pkh(cc, ccn);
        } else if (tid < 256) {
            const int u = tid - 128;     // rows 4u..4u+3, kk4 in [0,10)
            #pragma unroll
            for (int c = 0; c < 2; ++c) {
                float a0 = 0.f, a1 = 0.f, a2 = 0.f, a3 = 0.f;
                #pragma unroll
                for (int kk = 0; kk < 10; ++kk) {
                    float2 hp2 = *(const float2*)&smem[OFF_HP + c * 64 + 2 * kk];
                    unsigned int h0 = bcu(hp2.x), h1 = bcu(hp2.y);
                    float4 wA = *(const float4*)&smem[OFF_WHH + (kk * G4 + 4 * u) * 2];
                    float4 wB = *(const float4*)&smem[OFF_WHH + (kk * G4 + 4 * u + 2) * 2];
                    a0 = dot2(h0, bcu(wA.x), a0); a0 = dot2(h1, bcu(wA.y), a0);
                    a1 = dot2(h0, bcu(wA.z), a1); a1 = dot2(h1, bcu(wA.w), a1);
                    a2 = dot2(h0, bcu(wB.x), a2); a2 = dot2(h1, bcu(wB.y), a2);
                    a3 = dot2(h0, bcu(wB.z), a3); a3 = dot2(h1, bcu(wB.w), a3);
                }
                float4 v; v.x = a0; v.y = a1; v.z = a2; v.w = a3;
                *(float4*)&smf[OFF_GFA + c * G4 + 4 * u] = v;
            }
        } else {
            const int r0 = tid - 256, r1 = tid;   // kk4 in [10,32)
            float A0 = 0.f, A1 = 0.f, B0 = 0.f, B1v = 0.f;
            float C0 = 0.f, C1 = 0.f, D0 = 0.f, D1 = 0.f;
            #pragma unroll
            for (int kk = 10; kk < 32; ++kk) {
                float2 ha = *(const float2*)&smem[OFF_HP + 2 * kk];
                float2 hb = *(const float2*)&smem[OFF_HP + 64 + 2 * kk];
                float2 w0 = *(const float2*)&smem[OFF_WHH + (kk * G4 + r0) * 2];
                float2 w1 = *(const float2*)&smem[OFF_WHH + (kk * G4 + r1) * 2];
                A0 = dot2(bcu(ha.x), bcu(w0.x), A0);  A1 = dot2(bcu(ha.y), bcu(w0.y), A1);
                B0 = dot2(bcu(hb.x), bcu(w0.x), B0);  B1v = dot2(bcu(hb.y), bcu(w0.y), B1v);
                C0 = dot2(bcu(ha.x), bcu(w1.x), C0);  C1 = dot2(bcu(ha.y), bcu(w1.y), C1);
                D0 = dot2(bcu(hb.x), bcu(w1.x), D0);  D1 = dot2(bcu(hb.y), bcu(w1.y), D1);
            }
            smf[OFF_GFB + r0] = A0 + A1;        smf[OFF_GFB + G4 + r0] = B0 + B1v;
            smf[OFF_GFB + r1] = C0 + C1;        smf[OFF_GFB + G4 + r1] = D0 + D1;
        }
        __syncthreads();   // B2

        // ======== P5: gate finalize (36 cc-dots, hh+gm+bias) + loader writes ========
        {
            float gA = bias_j + gmA + smf[OFF_GFA + tid] + smf[OFF_GFB + tid];
            float gB = bias_j + gmB + smf[OFF_GFA + G4 + tid] + smf[OFF_GFB + G4 + tid];
            DOT18C(gA, OFF_CCP, 0);
            DOT18C(gB, OFF_CCP + 20, 0);
            smf[OFF_GFA + tid] = gA;
            smf[OFF_GFA + G4 + tid] = gB;
        }
        if (tid >= 256) {
            smf[lddst1] = pf1v;
            float vn = __shfl_xor(pf1v, 1);
            if (isd1 && !(f1 & 1)) smem[OFF_DP + (nxt * 2 + c1) * 20 + (f1 >> 1)] = pkh(pf1v, vn);
            if (ism1 && !(f1 & 1)) smem[OFF_MP + (nxt * 2 + c1) * 20 + (f1 >> 1)] = pkh(pf1v, vn);
            if (ldsrc2) smf[lddst2] = pf2v;
        }
        __syncthreads();   // B3

        // ======== P6: LSTM (w0-3) + gm(t+1) (all threads); no barrier (safe, see B1/B2) ========
        if (tid < 256) {
            const int c = tid >> 7, hidx = tid & 127;
            float ig = smf[OFF_GFA + c * G4 + hidx];
            float fg = smf[OFF_GFA + c * G4 + 128 + hidx];
            float gg = smf[OFF_GFA + c * G4 + 256 + hidx];
            float og = smf[OFF_GFA + c * G4 + 384 + hidx];
            c_reg = sigmoid_f(fg) * c_reg + sigmoid_f(ig) * tanh_f(gg);
            h_reg = sigmoid_f(og) * tanh_f(c_reg);
        }
        gmA = 0.f; gmB = 0.f;
        DOT18C(gmA, OFF_MP + nxt * 40, 18);
        DOT18C(gmB, OFF_MP + nxt * 40 + 20, 18);
    }

    // ---- per-block loss partial (fixed order -> deterministic) ----
    __syncthreads();
    if (tid < 128) {
        const int c = tid >> 6, f = tid & 63;
        if (f < Fn) smf[OFF_GFA + c * Fn + f] = loss_acc;
    }
    __syncthreads();
    if (tid == 0) {
        float sA = 0.f, sB = 0.f;
        for (int i = 0; i < Fn; ++i) { sA += smf[OFF_GFA + i]; sB += smf[OFF_GFA + Fn + i]; }
        float w0 = W_comb[0], w1 = W_comb[1], w2 = W_comb[2];
        float mx = fmaxf(w0, fmaxf(w1, w2));
        float e0 = expf(w0 - mx), e1 = expf(w1 - mx), e2 = expf(w2 - mx);
        float inv = 1.f / (e0 + e1 + e2);
        float wkA = ((kA == 0) ? e0 : (kA == 1) ? e1 : e2) * inv;
        float wkB = ((kB == 0) ? e0 : (kB == 1) ? e1 : e2) * inv;
        ws[LOSS_OFF + blockIdx.x] = sA * wkA + sB * wkB;
    }
}

// ---------------- k-reduction of imputations ----------------
__global__ void impute_reduce(const float* __restrict__ ws,
                              const float* __restrict__ W_comb,
                              float* __restrict__ out) {
    int idx = blockIdx.x * 256 + threadIdx.x;
    float w0 = W_comb[0], w1 = W_comb[1], w2 = W_comb[2];
    float mx = fmaxf(w0, fmaxf(w1, w2));
    float e0 = expf(w0 - mx), e1 = expf(w1 - mx), e2 = expf(w2 - mx);
    float inv = 1.f / (e0 + e1 + e2);
    const float* imp = ws + IMP_OFF;
    out[1 + idx] = (e0 * imp[idx] + e1 * imp[BTFn + idx] + e2 * imp[2 * BTFn + idx]) * inv;
}

// ---------------- final loss (192 per-block partials) ----------------
__global__ void loss_final(const float* __restrict__ ws,
                           const float* __restrict__ W_comb,
                           float* __restrict__ out) {
    int tid = threadIdx.x;
    __shared__ float red[256];
    const float* lp = ws + LOSS_OFF;
    red[tid] = (tid < 192) ? lp[tid] : 0.f;
    __syncthreads();
    for (int off = 128; off > 0; off >>= 1) {
        if (tid < off) red[tid] += red[tid + off];
        __syncthreads();
    }
    if (tid == 0) {
        float w0 = W_comb[0], w1 = W_comb[1], w2 = W_comb[2];
        float mx = fmaxf(w0, fmaxf(w1, w2));
        float e0 = expf(w0 - mx), e1 = expf(w1 - mx), e2 = expf(w2 - mx);
        float inv = 1.f / (e0 + e1 + e2);
        float wk0 = e0 * inv, wk1 = e1 * inv, wk2 = e2 * inv;
        float reg = 0.1f * (wk0 * (1.f / 24.f) + wk1 * (1.f / 168.f) + wk2 * (1.f / 720.f));
        out[0] = red[0] + (float)Tn * reg;
    }
}

extern "C" void kernel_launch(void* const* d_in, const int* in_sizes, int n_in,
                              void* d_out, int out_size, void* d_ws, size_t ws_size,
                              hipStream_t stream) {
    const float* data   = (const float*)d_in[0];
    const float* W_dh   = (const float*)d_in[1];
    const float* b_dh   = (const float*)d_in[2];
    const float* W_dx   = (const float*)d_in[3];
    const float* b_dx   = (const float*)d_in[4];
    const float* W_hist = (const float*)d_in[5];
    const float* b_hist = (const float*)d_in[6];
    const float* W_feat = (const float*)d_in[7];
    const float* b_feat = (const float*)d_in[8];
    const float* W_wc   = (const float*)d_in[9];
    const float* b_wc   = (const float*)d_in[10];
    const float* W_ih   = (const float*)d_in[11];
    const float* W_hh   = (const float*)d_in[12];
    const float* b_ih   = (const float*)d_in[13];
    const float* b_hh   = (const float*)d_in[14];
    const float* W_comb = (const float*)d_in[15];
    float* ws = (float*)d_ws;
    float* out = (float*)d_out;

    hipLaunchKernelGGL(prep_kernel, dim3(Tn), dim3(256), 0, stream, data, ws);
    hipLaunchKernelGGL(rits_main, dim3(Bn * 3 / 2), dim3(512), SMEM_WORDS * 4, stream,
                       data, W_dh, b_dh, W_dx, b_dx, W_hist, b_hist,
                       W_feat, b_feat, W_wc, b_wc, W_ih, W_hh, b_ih, b_hh, W_comb, ws);
    hipLaunchKernelGGL(impute_reduce, dim3(BTFn / 256), dim3(256), 0, stream, ws, W_comb, out);
    hipLaunchKernelGGL(loss_final, dim3(1), dim3(256), 0, stream, ws, W_comb, out);
}

// Round 9
// 1981.352 us; speedup vs baseline: 2.1468x; 1.1775x over previous
//
#include <hip/hip_runtime.h>
#include <math.h>

#define Bn 128
#define Tn 256
#define Fn 36
#define Hn 128
#define BTFn (Bn*Tn*Fn)
#define NCH 16
#define NBLK 24
#define TF 9216          // Tn*Fn

// ws float offsets
#define INVD_OFF 0
#define LOSS_OFF 102656
#define IMP_OFF  103040

// LDS word offsets
#define OFF_WHHF  0        // [mt<32][kt<4][l<64][4]  A-frags of W_hh : 32768
#define OFF_MSTG  32768    // [par2][36][16] f32 m staging            : 1152
#define OFF_HF    33920    // h B-frags [kt<4][256]                   : 1024
#define OFF_DF    34944    // d B-frags [par2][kt<2][256]             : 1024
#define OFF_GXMF  35968    // [gx;m] B-frags [par2][kt<3][256]        : 1536
#define OFF_CCMF  37504    // [cc;m] B-frags [par2][kt<3][256]        : 1536
#define OFF_XCF   39040    // xc B-frags [kt<2][256]                  : 512
#define OFF_INVD  39552    // 256
#define OFF_BIASG 39808    // 512
#define OFF_BH    40320    // 48
#define OFF_BF    40368    // 48
#define OFF_BWC   40416    // 48
#define OFF_LOSS  40464    // 192
#define SMEM_WORDS 40656   // *4 = 162624 B <= 163840

typedef _Float16 f16x8 __attribute__((ext_vector_type(8)));
typedef float f32x4 __attribute__((ext_vector_type(4)));
#define MFMA __builtin_amdgcn_mfma_f32_16x16x32_f16

__device__ __forceinline__ unsigned int pkh(float a, float b) {
    return __builtin_bit_cast(unsigned int, __builtin_amdgcn_cvt_pkrtz(a, b));
}
__device__ __forceinline__ float sigmoid_f(float x) {
    return __builtin_amdgcn_rcpf(1.f + __expf(-x));
}
__device__ __forceinline__ float tanh_f(float x) {
    return fmaf(2.f, __builtin_amdgcn_rcpf(1.f + __expf(-2.f * x)), -1.f);
}

// word offset of the u32 holding f16 pair (k, k+1) for column ch, within one frag buffer
#define FRAGW(k, c) (((((k) >> 5)) << 8) + (((16 * ((((k) & 31)) >> 3)) + (c)) << 2) + ((((k) & 7)) >> 1))

// ---------------- prep: inv-denom per t ----------------
__global__ void prep_kernel(const float* __restrict__ data,
                            float* __restrict__ ws) {
    int t = blockIdx.x;
    int tid = threadIdx.x;
    __shared__ float red[256];
    float s = 0.f;
    for (int idx = tid; idx < Bn * Fn; idx += 256) {
        int b = idx / Fn, f = idx - b * Fn;
        s += data[((size_t)(b * 24 + 1) * Tn + t) * Fn + f];
    }
    red[tid] = s;
    __syncthreads();
    for (int off = 128; off > 0; off >>= 1) {
        if (tid < off) red[tid] += red[tid + off];
        __syncthreads();
    }
    if (tid == 0) ws[INVD_OFF + t] = 1.f / (red[0] + 1e-5f);
}

// build an A-fragment (16x32 f16) from a row-major f32 matrix
#define INITF(dst, SRC, RR, CC, rowbase, kt, DIAG) do {                      \
    int _r = (rowbase) + (l & 15);                                           \
    _Pragma("unroll")                                                        \
    for (int _j = 0; _j < 8; ++_j) {                                         \
        int _k = (kt) * 32 + lg * 8 + _j;                                    \
        float _v = (_r < (RR) && _k < (CC)) ? (SRC)[_r * (CC) + _k] : 0.f;   \
        if ((DIAG) && _r == _k) _v = 0.f;                                    \
        (dst)[_j] = (_Float16)_v;                                            \
    }                                                                        \
} while (0)

// loader per-q setup / per-step macros
#define SETQ(N, Q) do { int _q = (Q), _kp = _q >> 4, _c = _q & 15, _k = 2 * _kp; \
    int _chain = blockIdx.x * NCH + _c; int _b = _chain / 3;                     \
    dp##N = data + (size_t)(_b * 24 + 2) * TF + _k;                              \
    mp##N = data + (size_t)(_b * 24 + 1) * TF + _k;                              \
    dfw##N = FRAGW(_k, _c);                                                      \
    gmw##N = FRAGW(_k + 36, _c);                                                 \
    msw##N = _k * 16 + _c;                                                       \
    wda##N = W_dx[_k * Fn + _k]; wdb##N = W_dx[(_k + 1) * Fn + (_k + 1)];        \
    bxa##N = b_dx[_k]; bxb##N = b_dx[_k + 1]; } while (0)

#define LDQ(N, T) do { dv##N = *(const float2*)(dp##N + (size_t)(T) * Fn); \
                       mv##N = *(const float2*)(mp##N + (size_t)(T) * Fn); } while (0)
#define STGQ(N, PAR) do { smf[OFF_MSTG + (PAR) * 576 + msw##N] = mv##N.x;       \
                          smf[OFF_MSTG + (PAR) * 576 + msw##N + 16] = mv##N.y; } while (0)
#define PKQ(N, PAR) do {                                                        \
    smem[OFF_DF + (PAR) * 512 + dfw##N] = pkh(dv##N.x, dv##N.y);                \
    float _g0 = __expf(-fmaxf(fmaf(dv##N.x, wda##N, bxa##N), 0.f));             \
    float _g1 = __expf(-fmaxf(fmaf(dv##N.y, wdb##N, bxb##N), 0.f));             \
    smem[OFF_GXMF + (PAR) * 768 + dfw##N] = pkh(_g0, _g1);                      \
    unsigned int _mw = pkh(mv##N.x, mv##N.y);                                   \
    smem[OFF_GXMF + (PAR) * 768 + gmw##N] = _mw;                                \
    smem[OFF_CCMF + (PAR) * 768 + gmw##N] = _mw; } while (0)

// ---------------- main: 1024 threads, 16 chains, MFMA pipeline ----------------
__global__ __launch_bounds__(1024) void rits_main(
    const float* __restrict__ data,
    const float* __restrict__ W_dh, const float* __restrict__ b_dh,
    const float* __restrict__ W_dx, const float* __restrict__ b_dx,
    const float* __restrict__ W_hist, const float* __restrict__ b_hist,
    const float* __restrict__ W_feat, const float* __restrict__ b_feat,
    const float* __restrict__ W_wc, const float* __restrict__ b_wc,
    const float* __restrict__ W_ih, const float* __restrict__ W_hh,
    const float* __restrict__ b_ih, const float* __restrict__ b_hh,
    const float* __restrict__ W_comb,
    float* __restrict__ ws)
{
    extern __shared__ unsigned int smem[];
    float* smf = (float*)smem;
    const int tid = threadIdx.x;
    const int wave = tid >> 6;
    const int l = tid & 63;
    const int ch = l & 15;
    const int lg = l >> 4;

    // ---- uniform init ----
    for (int i = tid; i < 32768; i += 1024) {
        int mt = i >> 10, kt = (i >> 8) & 3, li = (i >> 2) & 63, j2 = i & 3;
        int row = mt * 16 + (li & 15);
        int k = kt * 32 + (li >> 4) * 8 + 2 * j2;
        float2 wv = *(const float2*)&W_hh[row * Hn + k];
        smem[OFF_WHHF + i] = pkh(wv.x, wv.y);
    }
    for (int i = tid; i < 4608; i += 1024) smem[OFF_DF + i] = 0;   // DF..XCF contiguous zero
    for (int i = tid; i < Tn; i += 1024) smf[OFF_INVD + i] = ws[INVD_OFF + i];
    if (tid < 512) smf[OFF_BIASG + tid] = b_ih[tid] + b_hh[tid];
    if (tid < 48) {
        smf[OFF_BH + tid]  = (tid < Fn) ? b_hist[tid] : 0.f;
        smf[OFF_BF + tid]  = (tid < Fn) ? b_feat[tid] : 0.f;
        smf[OFF_BWC + tid] = (tid < Fn) ? b_wc[tid]   : 0.f;
    }

    // ---- role-private persistent state ----
    f16x8 wi00, wi01, wi02, wi10, wi11, wi12, wi20, wi21, wi22, wi30, wi31, wi32;
    f16x8 wdh0, wdh1;
    f32x4 bdhv = {0.f, 0.f, 0.f, 0.f};
    float hreg[4] = {0.f, 0.f, 0.f, 0.f}, creg[4] = {0.f, 0.f, 0.f, 0.f};
    f16x8 fw0, fw1, fw2, fw3, fw4, fw5, fw6, fw7, fw8;
    float wkk = 0.f, loss_acc = 0.f;
    const float *rtp = nullptr, *trp = nullptr, *sep = nullptr;
    float* impp = nullptr;
    int r0 = 0;
    const float *dp0 = nullptr, *mp0 = nullptr, *dp1 = nullptr, *mp1 = nullptr,
                *dp2 = nullptr, *mp2 = nullptr;
    int dfw0 = 0, gmw0 = 0, msw0 = 0, dfw1 = 0, gmw1 = 0, msw1 = 0,
        dfw2 = 0, gmw2 = 0, msw2 = 0;
    float wda0 = 0, wdb0 = 0, bxa0 = 0, bxb0 = 0, wda1 = 0, wdb1 = 0, bxa1 = 0, bxb1 = 0,
          wda2 = 0, wdb2 = 0, bxa2 = 0, bxb2 = 0;
    bool hasq2 = false;

    const int w = wave;
    if (wave < 8) {
        INITF(wi00, W_ih, 512, 72, (w +  0) * 16, 0, 0);
        INITF(wi01, W_ih, 512, 72, (w +  0) * 16, 1, 0);
        INITF(wi02, W_ih, 512, 72, (w +  0) * 16, 2, 0);
        INITF(wi10, W_ih, 512, 72, (w +  8) * 16, 0, 0);
        INITF(wi11, W_ih, 512, 72, (w +  8) * 16, 1, 0);
        INITF(wi12, W_ih, 512, 72, (w +  8) * 16, 2, 0);
        INITF(wi20, W_ih, 512, 72, (w + 16) * 16, 0, 0);
        INITF(wi21, W_ih, 512, 72, (w + 16) * 16, 1, 0);
        INITF(wi22, W_ih, 512, 72, (w + 16) * 16, 2, 0);
        INITF(wi30, W_ih, 512, 72, (w + 24) * 16, 0, 0);
        INITF(wi31, W_ih, 512, 72, (w + 24) * 16, 1, 0);
        INITF(wi32, W_ih, 512, 72, (w + 24) * 16, 2, 0);
        INITF(wdh0, W_dh, 128, 36, w * 16, 0, 0);
        INITF(wdh1, W_dh, 128, 36, w * 16, 1, 0);
        bdhv = *(const f32x4*)&b_dh[w * 16 + lg * 4];
    } else if (wave < 11) {
        int mt = wave - 8;
        r0 = mt * 16 + lg * 4;
        INITF(fw0, W_hist, Fn, Hn, mt * 16, 0, 0);
        INITF(fw1, W_hist, Fn, Hn, mt * 16, 1, 0);
        INITF(fw2, W_hist, Fn, Hn, mt * 16, 2, 0);
        INITF(fw3, W_hist, Fn, Hn, mt * 16, 3, 0);
        INITF(fw4, W_feat, Fn, Fn, mt * 16, 0, 1);
        INITF(fw5, W_feat, Fn, Fn, mt * 16, 1, 1);
        INITF(fw6, W_wc, Fn, 2 * Fn, mt * 16, 0, 0);
        INITF(fw7, W_wc, Fn, 2 * Fn, mt * 16, 1, 0);
        INITF(fw8, W_wc, Fn, 2 * Fn, mt * 16, 2, 0);
        int chain = blockIdx.x * NCH + ch;
        int b = chain / 3, k3 = chain - 3 * b;
        rtp = data + (size_t)(b * 24 + 3 + 3 * k3) * TF;
        trp = data + (size_t)(b * 24 + 4 + 3 * k3) * TF;
        sep = data + (size_t)(b * 24 + 5 + 3 * k3) * TF;
        impp = ws + IMP_OFF + (size_t)(k3 * Bn + b) * TF;
        float c0 = W_comb[0], c1 = W_comb[1], c2 = W_comb[2];
        float mx = fmaxf(c0, fmaxf(c1, c2));
        float e0 = expf(c0 - mx), e1 = expf(c1 - mx), e2 = expf(c2 - mx);
        wkk = ((k3 == 0) ? e0 : (k3 == 1) ? e1 : e2) / (e0 + e1 + e2);
    } else if (wave >= 14) {
        int ld = tid - 896;          // 0..127
        SETQ(0, ld);
        SETQ(1, ld + 128);
        hasq2 = (ld < 32);
        if (hasq2) SETQ(2, ld + 256);
    }
    __syncthreads();

    // ---- prologue: stage t=0 into parity 0 ----
    {
        float2 dv0, mv0, dv1, mv1, dv2, mv2;
        if (wave >= 14) {
            LDQ(0, 0); LDQ(1, 0); if (hasq2) LDQ(2, 0);
            STGQ(0, 0); STGQ(1, 0); if (hasq2) STGQ(2, 0);
            PKQ(0, 0); PKQ(1, 0); if (hasq2) PKQ(2, 0);
        }
    }
    __syncthreads();

    for (int t = 0; t < Tn; ++t) {
        const int p = t & 1, pn = p ^ 1;
        f32x4 rtv = {0, 0, 0, 0}, trv = {0, 0, 0, 0}, sev = {0, 0, 0, 0};
        float xh_[4], m_[4], cc_[4];
        float2 dv0, mv0, dv1, mv1, dv2, mv2;
        f32x4 ga0 = {0, 0, 0, 0}, ga1 = {0, 0, 0, 0}, ga2 = {0, 0, 0, 0}, ga3 = {0, 0, 0, 0};

        // ---------- S1: gamma_h decay + h-frag write | rt load | loader loads ----------
        if (wave < 8) {
            f32x4 gacc = {0, 0, 0, 0};
            f16x8 df0 = *(const f16x8*)&smem[OFF_DF + p * 512 + (l << 2)];
            f16x8 df1 = *(const f16x8*)&smem[OFF_DF + p * 512 + 256 + (l << 2)];
            gacc = MFMA(wdh0, df0, gacc, 0, 0, 0);
            gacc = MFMA(wdh1, df1, gacc, 0, 0, 0);
            #pragma unroll
            for (int r = 0; r < 4; ++r)
                hreg[r] *= __expf(-fmaxf(gacc[r] + bdhv[r], 0.f));
            int u0 = w * 16 + lg * 4;
            uint2 hw; hw.x = pkh(hreg[0], hreg[1]); hw.y = pkh(hreg[2], hreg[3]);
            *(uint2*)&smem[OFF_HF + FRAGW(u0, ch)] = hw;
        } else if (wave < 11) {
            rtv = *(const f32x4*)(rtp + (size_t)t * Fn + r0);
        } else if (wave >= 14) {
            LDQ(0, t + 1); LDQ(1, t + 1); if (hasq2) LDQ(2, t + 1);
        }
        __syncthreads();   // B1

        // ---------- S2: hh-gates MFMA | xh MFMA + xc | m staging write ----------
        if (wave < 8) {
            #pragma unroll
            for (int kt = 0; kt < 4; ++kt) {
                f16x8 hf = *(const f16x8*)&smem[OFF_HF + kt * 256 + (l << 2)];
                ga0 = MFMA(*(const f16x8*)&smem[OFF_WHHF + (((w +  0) * 4 + kt) << 8) + (l << 2)], hf, ga0, 0, 0, 0);
                ga1 = MFMA(*(const f16x8*)&smem[OFF_WHHF + (((w +  8) * 4 + kt) << 8) + (l << 2)], hf, ga1, 0, 0, 0);
                ga2 = MFMA(*(const f16x8*)&smem[OFF_WHHF + (((w + 16) * 4 + kt) << 8) + (l << 2)], hf, ga2, 0, 0, 0);
                ga3 = MFMA(*(const f16x8*)&smem[OFF_WHHF + (((w + 24) * 4 + kt) << 8) + (l << 2)], hf, ga3, 0, 0, 0);
            }
        } else if (wave < 11) {
            trv = *(const f32x4*)(trp + (size_t)t * Fn + r0);
            sev = *(const f32x4*)(sep + (size_t)t * Fn + r0);
            f32x4 xacc = {0, 0, 0, 0};
            xacc = MFMA(fw0, *(const f16x8*)&smem[OFF_HF +   0 + (l << 2)], xacc, 0, 0, 0);
            xacc = MFMA(fw1, *(const f16x8*)&smem[OFF_HF + 256 + (l << 2)], xacc, 0, 0, 0);
            xacc = MFMA(fw2, *(const f16x8*)&smem[OFF_HF + 512 + (l << 2)], xacc, 0, 0, 0);
            xacc = MFMA(fw3, *(const f16x8*)&smem[OFF_HF + 768 + (l << 2)], xacc, 0, 0, 0);
            const bool act = (r0 < Fn);
            float xc_[4];
            #pragma unroll
            for (int r = 0; r < 4; ++r) {
                xh_[r] = xacc[r] + smf[OFF_BH + r0 + r];
                m_[r]  = act ? smf[OFF_MSTG + p * 576 + (r0 + r) * 16 + ch] : 0.f;
                float rt = act ? rtv[r] : 0.f;
                xc_[r] = fmaf(m_[r], rt, (1.f - m_[r]) * xh_[r]);
            }
            if (act) {
                uint2 v; v.x = pkh(xc_[0], xc_[1]); v.y = pkh(xc_[2], xc_[3]);
                *(uint2*)&smem[OFF_XCF + FRAGW(r0, ch)] = v;
            }
        } else if (wave >= 14) {
            STGQ(0, pn); STGQ(1, pn); if (hasq2) STGQ(2, pn);
        }
        __syncthreads();   // B2

        // ---------- S3: zh+alpha MFMA, cc/loss/imp, cc-frag | loader packs ----------
        if (wave >= 8 && wave < 11) {
            f32x4 zacc = {0, 0, 0, 0}, aacc = {0, 0, 0, 0};
            zacc = MFMA(fw4, *(const f16x8*)&smem[OFF_XCF +   0 + (l << 2)], zacc, 0, 0, 0);
            zacc = MFMA(fw5, *(const f16x8*)&smem[OFF_XCF + 256 + (l << 2)], zacc, 0, 0, 0);
            aacc = MFMA(fw6, *(const f16x8*)&smem[OFF_GXMF + p * 768 +   0 + (l << 2)], aacc, 0, 0, 0);
            aacc = MFMA(fw7, *(const f16x8*)&smem[OFF_GXMF + p * 768 + 256 + (l << 2)], aacc, 0, 0, 0);
            aacc = MFMA(fw8, *(const f16x8*)&smem[OFF_GXMF + p * 768 + 512 + (l << 2)], aacc, 0, 0, 0);
            const bool act = (r0 < Fn);
            float invt = smf[OFF_INVD + t];
            f32x4 iv;
            #pragma unroll
            for (int r = 0; r < 4; ++r) {
                float zh  = zacc[r] + smf[OFF_BF + r0 + r];
                float al  = aacc[r] + smf[OFF_BWC + r0 + r];
                float chv = al * zh + (1.f - al) * xh_[r];
                float rt  = act ? rtv[r] : 0.f;
                cc_[r] = fmaf(m_[r], rt, (1.f - m_[r]) * chv);
                if (act) loss_acc += (fabsf(rt - xh_[r]) + fabsf(rt - zh) + fabsf(rt - chv)) * m_[r] * invt;
                iv[r] = cc_[r] + sev[r] + trv[r];
            }
            if (act) {
                *(f32x4*)(impp + (size_t)t * Fn + r0) = iv;
                uint2 v; v.x = pkh(cc_[0], cc_[1]); v.y = pkh(cc_[2], cc_[3]);
                *(uint2*)&smem[OFF_CCMF + p * 768 + FRAGW(r0, ch)] = v;
            }
        } else if (wave >= 14) {
            PKQ(0, pn); PKQ(1, pn); if (hasq2) PKQ(2, pn);
        }
        __syncthreads();   // B3

        // ---------- S4: ih-gates MFMA + LSTM (gate waves; others run ahead to S1) ----------
        if (wave < 8) {
            f16x8 cf0 = *(const f16x8*)&smem[OFF_CCMF + p * 768 +   0 + (l << 2)];
            f16x8 cf1 = *(const f16x8*)&smem[OFF_CCMF + p * 768 + 256 + (l << 2)];
            f16x8 cf2 = *(const f16x8*)&smem[OFF_CCMF + p * 768 + 512 + (l << 2)];
            ga0 = MFMA(wi00, cf0, ga0, 0, 0, 0);
            ga0 = MFMA(wi01, cf1, ga0, 0, 0, 0);
            ga0 = MFMA(wi02, cf2, ga0, 0, 0, 0);
            ga1 = MFMA(wi10, cf0, ga1, 0, 0, 0);
            ga1 = MFMA(wi11, cf1, ga1, 0, 0, 0);
            ga1 = MFMA(wi12, cf2, ga1, 0, 0, 0);
            ga2 = MFMA(wi20, cf0, ga2, 0, 0, 0);
            ga2 = MFMA(wi21, cf1, ga2, 0, 0, 0);
            ga2 = MFMA(wi22, cf2, ga2, 0, 0, 0);
            ga3 = MFMA(wi30, cf0, ga3, 0, 0, 0);
            ga3 = MFMA(wi31, cf1, ga3, 0, 0, 0);
            ga3 = MFMA(wi32, cf2, ga3, 0, 0, 0);
            int u0 = w * 16 + lg * 4;
            #pragma unroll
            for (int r = 0; r < 4; ++r) {
                float ig = ga0[r] + smf[OFF_BIASG + u0 + r];
                float fg = ga1[r] + smf[OFF_BIASG + 128 + u0 + r];
                float gg = ga2[r] + smf[OFF_BIASG + 256 + u0 + r];
                float og = ga3[r] + smf[OFF_BIASG + 384 + u0 + r];
                creg[r] = sigmoid_f(fg) * creg[r] + sigmoid_f(ig) * tanh_f(gg);
                hreg[r] = sigmoid_f(og) * tanh_f(creg[r]);
            }
        }
        // no barrier: S1(t+1) h-frag writes race nothing (last HF readers ended at B2),
        // DF/GXMF/CCMF accesses are parity-separated, CCMF[p] readers (here) vs
        // S3(t+1) writers of CCMF[pn] are distinct and barrier-ordered anyway.
    }

    // ---- loss partial (fixed order -> deterministic) ----
    if (wave >= 8 && wave < 11) smf[OFF_LOSS + (wave - 8) * 64 + l] = loss_acc * wkk;
    __syncthreads();
    if (tid == 0) {
        float s = 0.f;
        for (int i = 0; i < 192; ++i) s += smf[OFF_LOSS + i];
        ws[LOSS_OFF + blockIdx.x] = s;
    }
}

// ---------------- k-reduction of imputations ----------------
__global__ void impute_reduce(const float* __restrict__ ws,
                              const float* __restrict__ W_comb,
                              float* __restrict__ out) {
    int idx = blockIdx.x * 256 + threadIdx.x;
    float w0 = W_comb[0], w1 = W_comb[1], w2 = W_comb[2];
    float mx = fmaxf(w0, fmaxf(w1, w2));
    float e0 = expf(w0 - mx), e1 = expf(w1 - mx), e2 = expf(w2 - mx);
    float inv = 1.f / (e0 + e1 + e2);
    const float* imp = ws + IMP_OFF;
    out[1 + idx] = (e0 * imp[idx] + e1 * imp[BTFn + idx] + e2 * imp[2 * BTFn + idx]) * inv;
}

// ---------------- final loss (24 per-block partials) ----------------
__global__ void loss_final(const float* __restrict__ ws,
                           const float* __restrict__ W_comb,
                           float* __restrict__ out) {
    if (threadIdx.x == 0) {
        const float* lp = ws + LOSS_OFF;
        float s = 0.f;
        for (int i = 0; i < NBLK; ++i) s += lp[i];
        float w0 = W_comb[0], w1 = W_comb[1], w2 = W_comb[2];
        float mx = fmaxf(w0, fmaxf(w1, w2));
        float e0 = expf(w0 - mx), e1 = expf(w1 - mx), e2 = expf(w2 - mx);
        float inv = 1.f / (e0 + e1 + e2);
        float wk0 = e0 * inv, wk1 = e1 * inv, wk2 = e2 * inv;
        float reg = 0.1f * (wk0 * (1.f / 24.f) + wk1 * (1.f / 168.f) + wk2 * (1.f / 720.f));
        out[0] = s + (float)Tn * reg;
    }
}

extern "C" void kernel_launch(void* const* d_in, const int* in_sizes, int n_in,
                              void* d_out, int out_size, void* d_ws, size_t ws_size,
                              hipStream_t stream) {
    const float* data   = (const float*)d_in[0];
    const float* W_dh   = (const float*)d_in[1];
    const float* b_dh   = (const float*)d_in[2];
    const float* W_dx   = (const float*)d_in[3];
    const float* b_dx   = (const float*)d_in[4];
    const float* W_hist = (const float*)d_in[5];
    const float* b_hist = (const float*)d_in[6];
    const float* W_feat = (const float*)d_in[7];
    const float* b_feat = (const float*)d_in[8];
    const float* W_wc   = (const float*)d_in[9];
    const float* b_wc   = (const float*)d_in[10];
    const float* W_ih   = (const float*)d_in[11];
    const float* W_hh   = (const float*)d_in[12];
    const float* b_ih   = (const float*)d_in[13];
    const float* b_hh   = (const float*)d_in[14];
    const float* W_comb = (const float*)d_in[15];
    float* ws = (float*)d_ws;
    float* out = (float*)d_out;

    hipLaunchKernelGGL(prep_kernel, dim3(Tn), dim3(256), 0, stream, data, ws);
    hipLaunchKernelGGL(rits_main, dim3(NBLK), dim3(1024), SMEM_WORDS * 4, stream,
                       data, W_dh, b_dh, W_dx, b_dx, W_hist, b_hist,
                       W_feat, b_feat, W_wc, b_wc, W_ih, W_hh, b_ih, b_hh, W_comb, ws);
    hipLaunchKernelGGL(impute_reduce, dim3(BTFn / 256), dim3(256), 0, stream, ws, W_comb, out);
    hipLaunchKernelGGL(loss_final, dim3(1), dim3(64), 0, stream, ws, W_comb, out);
}